// Round 1
// baseline (357.883 us; speedup 1.0000x reference)
//
#include <hip/hip_runtime.h>

// image2patch: out[b, i*126+j, r*6+c] = x[b, 0, 2*i + r, 2*j + c]
// IMAGE_SIZE=256, PSIZE=6, STRIDE=2, NPOS=126, BATCH=128, fp32.
// Output 292.6 MB, input 33.5 MB -> memory(write)-bound. One thread per
// output float4 (patch = 36 floats = 144 B, 16B-aligned, so each float4
// is within one patch): stores are fully coalesced 16B/lane.

#define IMG 256
#define PSZ 6
#define NPOS 126
#define BATCHN 128
#define PATCH_ELEMS (PSZ * PSZ)                  // 36
#define PER_BATCH (NPOS * NPOS * PATCH_ELEMS)    // 571536
#define TOTAL_ELEMS (BATCHN * PER_BATCH)         // 73,156,608
#define TOTAL_VEC4 (TOTAL_ELEMS / 4)             // 18,289,152

__global__ __launch_bounds__(256) void image2patch_kernel(
    const float* __restrict__ x, float* __restrict__ out) {
  const int tid4 = blockIdx.x * blockDim.x + threadIdx.x;
  const int flat = tid4 * 4;  // first output element of this thread's float4

  const int b   = flat / PER_BATCH;
  const int rem = flat - b * PER_BATCH;
  const int p   = rem / PATCH_ELEMS;       // patch index i*126 + j
  const int k   = rem - p * PATCH_ELEMS;   // 0,4,...,32 within patch
  const int i   = p / NPOS;
  const int j   = p - i * NPOS;

  // top-left corner of the patch in the image
  const float* img = x + (size_t)b * (IMG * IMG) + (2 * i) * IMG + (2 * j);

  float4 v;
  {
    int kk = k;     int r = kk / PSZ, c = kk - PSZ * r; v.x = img[r * IMG + c];
    kk = k + 1;     r = kk / PSZ;     c = kk - PSZ * r; v.y = img[r * IMG + c];
    kk = k + 2;     r = kk / PSZ;     c = kk - PSZ * r; v.z = img[r * IMG + c];
    kk = k + 3;     r = kk / PSZ;     c = kk - PSZ * r; v.w = img[r * IMG + c];
  }
  reinterpret_cast<float4*>(out)[tid4] = v;
}

extern "C" void kernel_launch(void* const* d_in, const int* in_sizes, int n_in,
                              void* d_out, int out_size, void* d_ws, size_t ws_size,
                              hipStream_t stream) {
  const float* x = (const float*)d_in[0];
  float* out = (float*)d_out;
  // 18,289,152 float4s / 256 threads = 71,442 blocks exactly
  image2patch_kernel<<<TOTAL_VEC4 / 256, 256, 0, stream>>>(x, out);
}

// Round 2
// 313.718 us; speedup vs baseline: 1.1408x; 1.1408x over previous
//
#include <hip/hip_runtime.h>

// image2patch: out[b, i*126+j, r*6+c] = x[b, 0, 2*i + r, 2*j + c]
// IMAGE_SIZE=256, PSIZE=6, STRIDE=2, NPOS=126, BATCH=128, fp32.
//
// R1 lesson: coalesced stores + divergent scalar global loads = read-path
// TA/TD serialization (~12 cache lines per wave-load-instr). Fix: stage the
// 6 image rows each block needs into LDS with coalesced float4 loads; do the
// scatter-gather out of LDS (ds_read_b32 ~5.8cyc, bank-padded stride 257).
//
// Block = (b, i): loads rows 2i..2i+5 (6 KB), writes 126 patches = 4536
// floats = 1134 float4, all global traffic fully coalesced.

#define IMG 256
#define PSZ 6
#define NPOS 126
#define BATCHN 128
#define LDSW 257                 // +1 float pad: bank = (r + 2j + c) % 32, mixed parity
#define VECS_PER_BAND 1134       // 126 patches * 36 floats / 4

__global__ __launch_bounds__(256) void image2patch_kernel(
    const float* __restrict__ x, float* __restrict__ out) {
  __shared__ float tile[PSZ * LDSW];

  const int blk = blockIdx.x;            // b * 126 + i
  const int b = blk / NPOS;
  const int i = blk - b * NPOS;
  const int t = threadIdx.x;

  // ---- stage rows 2i..2i+5 into LDS (coalesced float4 global loads) ----
  const float* src = x + (size_t)b * (IMG * IMG) + (size_t)(2 * i) * IMG;
  for (int idx = t; idx < PSZ * (IMG / 4); idx += 256) {   // 384 float4s
    const int row  = idx >> 6;           // 64 float4 per image row
    const int col4 = idx & 63;
    float4 v = reinterpret_cast<const float4*>(src + row * IMG)[col4];
    float* d = &tile[row * LDSW + col4 * 4];
    d[0] = v.x; d[1] = v.y; d[2] = v.z; d[3] = v.w;        // LDSW odd -> scalar writes
  }
  __syncthreads();

  // ---- emit 126 patches: 1134 float4 coalesced stores, LDS gather ----
  float4* outp = reinterpret_cast<float4*>(
      out + ((size_t)b * (NPOS * NPOS) + (size_t)i * NPOS) * (PSZ * PSZ));
  for (int q = t; q < VECS_PER_BAND; q += 256) {
    const int f  = q * 4;                 // flat float index in the band
    const int j  = f / 36;                // patch column
    const int k0 = f - j * 36;            // 0,4,...,32
    const int jj = 2 * j;
    float4 v;
    { const int k = k0;     const int r = k / PSZ, c = k - PSZ * r; v.x = tile[r * LDSW + jj + c]; }
    { const int k = k0 + 1; const int r = k / PSZ, c = k - PSZ * r; v.y = tile[r * LDSW + jj + c]; }
    { const int k = k0 + 2; const int r = k / PSZ, c = k - PSZ * r; v.z = tile[r * LDSW + jj + c]; }
    { const int k = k0 + 3; const int r = k / PSZ, c = k - PSZ * r; v.w = tile[r * LDSW + jj + c]; }
    outp[q] = v;
  }
}

extern "C" void kernel_launch(void* const* d_in, const int* in_sizes, int n_in,
                              void* d_out, int out_size, void* d_ws, size_t ws_size,
                              hipStream_t stream) {
  const float* x = (const float*)d_in[0];
  float* out = (float*)d_out;
  image2patch_kernel<<<BATCHN * NPOS, 256, 0, stream>>>(x, out);
}